// Round 6
// baseline (217.082 us; speedup 1.0000x reference)
//
#include <hip/hip_runtime.h>
#include <stdint.h>
#include <stddef.h>

#define CD 512
#define KC 1024
#define NR 32768  // total rows (32*1024)

typedef __attribute__((ext_vector_type(8))) short short8_t;
typedef __attribute__((ext_vector_type(8))) __bf16 bf16x8_t;
typedef __attribute__((ext_vector_type(4))) float f32x4_t;

__device__ __forceinline__ uint16_t f2bf(float f) {
  uint32_t u = __float_as_uint(f);
  u += 0x7fffu + ((u >> 16) & 1u);
  return (uint16_t)(u >> 16);
}
__device__ __forceinline__ float bf2f(uint16_t h) {
  return __uint_as_float(((uint32_t)h) << 16);
}
__device__ __forceinline__ float soft_sign(float x) {
  // 2*sigmoid(100x)-1 ; fast path (rel err ~1e-7 -> dot shift ~2e-6 << margin)
  float e = __expf(-100.0f * x);
  float s = __builtin_amdgcn_rcpf(1.0f + e);
  return fmaf(2.0f, s, -1.0f);
}

// ---- codebook -> bf16 plain [k][c] + sign pack[c/32][k] + counts zero ----
__global__ __launch_bounds__(256) void k_cb(const float* __restrict__ cb,
                                            uint16_t* __restrict__ cbb,
                                            uint32_t* __restrict__ pack,
                                            int* __restrict__ counts) {
  int i = blockIdx.x * 256 + threadIdx.x;  // 524288
  float v = cb[i];
  cbb[i] = f2bf(v);
  int k = i >> 9, c = i & 511;
  unsigned long long m = __ballot(v > 0.0f);
  int lane = threadIdx.x & 63;
  if ((lane & 31) == 0) pack[((c >> 5) << 10) + k] = (uint32_t)(m >> (lane & 32));
  if (i < KC) counts[i] = 0;
}

__device__ __forceinline__ void gl_lds16(const uint16_t* g, uint16_t* l) {
  __builtin_amdgcn_global_load_lds((const uint32_t*)g, (uint32_t*)l, 16, 0, 0);
}

// ------------- fused prep + GEMM + argmin: block = 64 p-rows, full K -------------
// LDS map (bytes): [0,32K) A: 4 bufs x 8KB (128 k-rows x 32 c, granule-swizzled);
//   fill scratch raw[64][64]f32 aliases [0,16K).  [32K,96K) B-hi [16 cc][64 r][32 c];
//   [96K,160K) B-lo.  512 thr = 8 waves (4 kg x 2 pg), 2 waves/SIMD.
// 128 steps = kt 0..7 (128 codes) x cc 0..15 (32 c). Depth-4 A prefetch, vmcnt(2).
// Granule swizzle (both sides): data (row, g) stored at granule g ^ ((row>>1)&3).
__global__ __launch_bounds__(512, 1) void k_gemm(const uint16_t* __restrict__ cbb,
                                                 const float* __restrict__ x,
                                                 int* __restrict__ idx,
                                                 int* __restrict__ counts) {
  extern __shared__ uint8_t smem[];
  uint16_t* lds = (uint16_t*)smem;

  const int tid = threadIdx.x;
  const int lane = tid & 63, wid = tid >> 6;
  const int kg = wid >> 1, pg = wid & 1;
  const int g = lane >> 4, r15 = lane & 15;
  const int blk = blockIdx.x;  // 512
  const int n0 = blk << 6;
  const int b = blk >> 4, p0 = (blk & 15) << 6;

  // A staging: thread tid fills dest granule tid of buf (linear for global_load_lds);
  // inverse-swizzled source granule so swizzled reads see (row, g) at g^((row>>1)&3).
  const int srow_t = tid >> 2;                    // 0..127
  const int sg_t = (tid & 3) ^ ((tid >> 3) & 3);  // source 8-elem granule
  const uint16_t* sbase = cbb + ((size_t)srow_t << 9) + (sg_t << 3);
  auto stageA = [&](int u) {  // u = step 0..127, buf = u&3
    gl_lds16(sbase + ((size_t)(u >> 4) << 16) + ((u & 15) << 5),
             lds + ((u & 3) << 12) + (tid << 3));
  };

  // ---- fill: x -> soft_sign -> split bf16 into resident B, + f64 row norms ----
  float* raw = (float*)smem;  // 16 KB scratch (A bufs 0-1), XOR-swizzled slots
  const float* xb = x + (((size_t)b) << 19) + p0;
  const int fr = tid >> 3, foc = tid & 7;  // row 0..63, octet 0..7
  double nsum = 0.0;
  for (int ch = 0; ch < 8; ++ch) {
    int c0 = ch << 6;
#pragma unroll
    for (int it = 0; it < 2; ++it) {
      int u = (it << 9) + tid;
      int cr = u >> 4, q = u & 15;
      const float4 v =
          *reinterpret_cast<const float4*>(xb + (size_t)(c0 + cr) * 1024 + (q << 2));
      *reinterpret_cast<float4*>(raw + (cr << 6) +
                                 ((q << 2) ^ ((((cr >> 3) & 7)) << 2))) = v;
    }
    __syncthreads();
    short8_t h8, l8;
    double ls = 0.0;
#pragma unroll
    for (int j = 0; j < 8; ++j) {
      int c = (foc << 3) + j;
      float xs = soft_sign(raw[(c << 6) + (fr ^ (foc << 2))]);
      uint16_t h = f2bf(xs);
      uint16_t l = f2bf(xs - bf2f(h));
      h8[j] = (short)h;
      l8[j] = (short)l;
      float sq = xs * xs;
      ls += (double)sq;
    }
    nsum += ls;
    int cc = (ch << 1) + (foc >> 2);
    int gp = (foc & 3) ^ ((fr >> 1) & 3);  // swizzled write granule
    uint16_t* bwp = (uint16_t*)(smem + 32768) + (cc << 11) + (fr << 5) + (gp << 3);
    *reinterpret_cast<short8_t*>(bwp) = h8;
    *reinterpret_cast<short8_t*>(bwp + 32768) = l8;  // lo at +64KB
    __syncthreads();
  }
  {  // norms: deterministic octet butterfly, park in raw, read s_p
    double s = nsum;
    s += __shfl_xor(s, 1);
    s += __shfl_xor(s, 2);
    s += __shfl_xor(s, 4);
    if (foc == 0) raw[fr] = (float)s + 512.0f;
  }
  __syncthreads();
  float s_p[2];
#pragma unroll
  for (int ac = 0; ac < 2; ++ac) s_p[ac] = raw[(pg << 5) + (ac << 4) + r15];
  __syncthreads();  // raw reads done before prologue stages overwrite A bufs

  // per-thread constant fragment offsets (swizzled)
  int offA[2], offB[2];
#pragma unroll
  for (int ar = 0; ar < 2; ++ar) {
    int row = (kg << 5) + (ar << 4) + r15;
    offA[ar] = (row << 5) + ((g ^ ((row >> 1) & 3)) << 3);
  }
#pragma unroll
  for (int ac = 0; ac < 2; ++ac) {
    int row = (pg << 5) + (ac << 4) + r15;
    offB[ac] = (row << 5) + ((g ^ ((row >> 1) & 3)) << 3);
  }

  stageA(0);
  stageA(1);
  stageA(2);

  float best_d[2];
  int best_k[2];
#pragma unroll
  for (int ac = 0; ac < 2; ++ac) { best_d[ac] = 3.4e38f; best_k[ac] = 0; }

  f32x4_t acc[2][2];
  for (int s = 0; s < 128; ++s) {
    int kt = s >> 4, cc = s & 15;
    // oldest in-flight stage (= step s) landed for this thread; then block-wide sync
    asm volatile("s_waitcnt vmcnt(2)" ::: "memory");
    __builtin_amdgcn_s_barrier();
    asm volatile("" ::: "memory");
    // prefetch step s+3 (wraps at tail to keep the vmcnt invariant; targets are
    // buffers already consumed — safe)
    stageA((s + 3) & 127);

    if (cc == 0) {
#pragma unroll
      for (int i = 0; i < 2; ++i)
#pragma unroll
        for (int j = 0; j < 2; ++j) acc[i][j] = (f32x4_t){0.f, 0.f, 0.f, 0.f};
    }

    const uint16_t* A = lds + ((s & 3) << 12);
    const uint16_t* Bh = (uint16_t*)(smem + 32768) + (cc << 11);
    bf16x8_t af[2], fbh[2], fbl[2];
#pragma unroll
    for (int ar = 0; ar < 2; ++ar)
      af[ar] = __builtin_bit_cast(bf16x8_t, *(const short8_t*)(A + offA[ar]));
#pragma unroll
    for (int ac = 0; ac < 2; ++ac) {
      fbh[ac] = __builtin_bit_cast(bf16x8_t, *(const short8_t*)(Bh + offB[ac]));
      fbl[ac] =
          __builtin_bit_cast(bf16x8_t, *(const short8_t*)(Bh + 32768 + offB[ac]));
    }
#pragma unroll
    for (int ar = 0; ar < 2; ++ar)
#pragma unroll
      for (int ac = 0; ac < 2; ++ac) {
        acc[ar][ac] =
            __builtin_amdgcn_mfma_f32_16x16x32_bf16(af[ar], fbh[ac], acc[ar][ac], 0, 0, 0);
        acc[ar][ac] =
            __builtin_amdgcn_mfma_f32_16x16x32_bf16(af[ar], fbl[ac], acc[ar][ac], 0, 0, 0);
      }

    if (cc == 15) {  // fold 128-code tile into running argmin
      int kbase = (kt << 7) + (kg << 5);
#pragma unroll
      for (int ar = 0; ar < 2; ++ar)
#pragma unroll
        for (int ac = 0; ac < 2; ++ac)
#pragma unroll
          for (int rg = 0; rg < 4; ++rg) {
            float d = fmaf(-2.0f, acc[ar][ac][rg], s_p[ac]);  // fl(s - 2*dot)
            int kk = kbase + (ar << 4) + (g << 2) + rg;
            bool better = (d < best_d[ac]) || (d == best_d[ac] && kk < best_k[ac]);
            if (better) { best_d[ac] = d; best_k[ac] = kk; }
          }
    }
  }

  // merge g-groups (lex order: min d, then min k)
  float rd0, rd1;
  int rk0, rk1;
  {
    float d = best_d[0];
    int k = best_k[0];
#pragma unroll
    for (int m = 16; m <= 32; m <<= 1) {
      float od = __shfl_xor(d, m);
      int ok = __shfl_xor(k, m);
      if (od < d || (od == d && ok < k)) { d = od; k = ok; }
    }
    rd0 = d; rk0 = k;
  }
  {
    float d = best_d[1];
    int k = best_k[1];
#pragma unroll
    for (int m = 16; m <= 32; m <<= 1) {
      float od = __shfl_xor(d, m);
      int ok = __shfl_xor(k, m);
      if (od < d || (od == d && ok < k)) { d = od; k = ok; }
    }
    rd1 = d; rk1 = k;
  }
  // drain wrap-stages before reusing LDS
  asm volatile("s_waitcnt vmcnt(0)" ::: "memory");
  float* sd = (float*)smem;
  int* sk = (int*)(smem + 1024);
  __syncthreads();
  if (g < 2) {
    float dv = (g == 0) ? rd0 : rd1;
    int kv = (g == 0) ? rk0 : rk1;
    sd[(kg << 6) + (pg << 5) + (g << 4) + r15] = dv;
    sk[(kg << 6) + (pg << 5) + (g << 4) + r15] = kv;
  }
  __syncthreads();
  if (tid < 64) {
    float d0 = sd[tid];
    int k0 = sk[tid];
#pragma unroll
    for (int kgi = 1; kgi < 4; ++kgi) {
      float d1 = sd[(kgi << 6) + tid];
      int k1 = sk[(kgi << 6) + tid];
      if (d1 < d0 || (d1 == d0 && k1 < k0)) { d0 = d1; k0 = k1; }
    }
    idx[n0 + tid] = k0;
    atomicAdd(&counts[k0], 1);
  }
}

// ------- gather via bit-packed codebook in LDS; block 0 also emits scalars -------
__global__ __launch_bounds__(256) void k_gather(const int* __restrict__ idx,
                                                const uint32_t* __restrict__ pack,
                                                const int* __restrict__ counts,
                                                float* __restrict__ out) {
  __shared__ uint32_t lp[16384];  // 64 KB sign table
  int tid = threadIdx.x;
  if (blockIdx.x == 0) {  // perplexity scalars (counts final after k_gemm)
    float local = 0.0f;
    for (int i = tid; i < KC; i += 256) {
      int c = counts[i];
      if (c > 0) {
        float p = (float)c * (1.0f / 32768.0f);
        local += p * logf(p);
      }
    }
#pragma unroll
    for (int m = 1; m < 64; m <<= 1) local += __shfl_xor(local, m);
    __shared__ float wsum[4];
    if ((tid & 63) == 0) wsum[tid >> 6] = local;
    __syncthreads();
    if (tid == 0) {
      float entropy = -(wsum[0] + wsum[1] + wsum[2] + wsum[3]);
      float pl = 1.0f / expf(entropy);
      out[16777216] = pl;
      out[16777217] = 0.25f * pl;
    }
  }
#pragma unroll
  for (int i = 0; i < 16; ++i)
    reinterpret_cast<uint4*>(lp)[i * 256 + tid] =
        reinterpret_cast<const uint4*>(pack)[i * 256 + tid];
  __syncthreads();
  int base = blockIdx.x * 2048;  // grid 2048
  for (int it = 0; it < 8; ++it) {
    int t = base + it * 256 + tid;
    int pq = t & 255;
    int c = (t >> 8) & 511;
    int b = t >> 17;
    int4 iv = reinterpret_cast<const int4*>(idx)[(b << 8) + pq];
    int cw = c >> 5, cbit = c & 31;
    float4 r;
    r.x = ((lp[(cw << 10) + iv.x] >> cbit) & 1) ? 1.0f : -1.0f;
    r.y = ((lp[(cw << 10) + iv.y] >> cbit) & 1) ? 1.0f : -1.0f;
    r.z = ((lp[(cw << 10) + iv.z] >> cbit) & 1) ? 1.0f : -1.0f;
    r.w = ((lp[(cw << 10) + iv.w] >> cbit) & 1) ? 1.0f : -1.0f;
    reinterpret_cast<float4*>(out)[t] = r;
  }
}

extern "C" void kernel_launch(void* const* d_in, const int* in_sizes, int n_in,
                              void* d_out, int out_size, void* d_ws, size_t ws_size,
                              hipStream_t stream) {
  (void)in_sizes; (void)n_in; (void)out_size; (void)ws_size;
  const float* x = (const float*)d_in[0];
  const float* cb = (const float*)d_in[1];
  float* out = (float*)d_out;

  uint8_t* ws = (uint8_t*)d_ws;
  uint16_t* cbb = (uint16_t*)ws;                               // 1 MB
  int* idx = (int*)(ws + 1048576);                             // 128 KB
  int* counts = (int*)(ws + 1048576 + 131072);                 // 4 KB
  uint32_t* pack = (uint32_t*)(ws + 1048576 + 131072 + 4096);  // 64 KB

  hipFuncSetAttribute((const void*)k_gemm, hipFuncAttributeMaxDynamicSharedMemorySize,
                      163840);

  k_cb<<<2048, 256, 0, stream>>>(cb, cbb, pack, counts);
  k_gemm<<<512, 512, 163840, stream>>>(cbb, x, idx, counts);
  k_gather<<<2048, 256, 0, stream>>>(idx, pack, counts, out);
}